// Round 6
// baseline (224.136 us; speedup 1.0000x reference)
//
#include <hip/hip_runtime.h>
#include <cstdint>
#include <cstddef>

typedef _Float16 f16;
typedef f16 f16x8 __attribute__((ext_vector_type(8)));
typedef f16 f16x4 __attribute__((ext_vector_type(4)));
typedef float f32x4 __attribute__((ext_vector_type(4)));

#define SEQ 4096
#define DH 128
#define QKV_LD 384   // 3*DH
#define LOG2E 1.44269504f
#define DEFER_THR 4.0f

__device__ __forceinline__ float fast_exp2(float x) {
#if __has_builtin(__builtin_amdgcn_exp2f)
  return __builtin_amdgcn_exp2f(x);
#else
  return exp2f(x);
#endif
}

// async global->LDS DMA, 16B per lane. LDS dest MUST be wave-uniform base + lane*16.
__device__ __forceinline__ void gl_lds16(const void* g, void* l) {
  __builtin_amdgcn_global_load_lds((const __attribute__((address_space(1))) void*)g,
                                   (__attribute__((address_space(3))) void*)l, 16, 0, 0);
}

// ---------------- W fp32 -> fp16 (+ zero split-K stripe counters) ----------------
__global__ __launch_bounds__(256) void cvt_w_kernel(const float4* __restrict__ W,
                                                    f16x4* __restrict__ Wh,
                                                    int* __restrict__ cnt) {
  int i = blockIdx.x * 256 + threadIdx.x;
  if (blockIdx.x == 0 && threadIdx.x < 64) cnt[threadIdx.x] = 0;  // ws is re-poisoned
  float4 v = W[i];
  f16x4 h; h[0] = (f16)v.x; h[1] = (f16)v.y; h[2] = (f16)v.z; h[3] = (f16)v.w;
  Wh[i] = h;
}

// ---------------- QKV GEMM + fused split-K reduction ----------------
// BM=64, BN=384, A staged at BK=128. Grid (64, SPLITS) = 512 blocks -> 2/CU.
// B staged by global_load_lds into unpadded XOR-swizzled LDS; A prefetched in
// regs (T14). Partials in REGISTER layout ([split][mblk][p24][tid][4], f16x4).
// The LAST block to finish a stripe (device-scope atomic counter + fences)
// reduces the stripe in-kernel: +bias, Q-columns pre-scaled by log2(e),
// V-columns transposed via an LDS tile (aliasing dead Bx) into Vt[128][4096].
template <int SPLITS>
__global__ __launch_bounds__(256, 2) void gemm_qkv_fused(const float* __restrict__ x,
                                                         const f16* __restrict__ Wh,
                                                         const float* __restrict__ bias,
                                                         f16* __restrict__ part,
                                                         int* __restrict__ cnt,
                                                         f16* __restrict__ qkv,
                                                         f16* __restrict__ Vt) {
  __shared__ __align__(16) char smem_raw[66560];       // 17408 (Ax) + 49152 (Bx)
  f16 (*Ax)[136] = (f16(*)[136])smem_raw;              // 64 x (128+8 pad)
  f16* Bx = (f16*)(smem_raw + 17408);                  // unpadded 384x64, swizzled chunks
  f16 (*Vl)[72] = (f16(*)[72])(smem_raw + 17408);      // reducer alias: 128 x (64+8)
  __shared__ int amLast;

  const int bx = blockIdx.x;
  const int m0 = bx * 64;
  const int split = blockIdx.y;
  const int kc = SEQ / SPLITS;
  const int k0 = split * kc;
  const int tid = threadIdx.x;
  const int lane = tid & 63;
  const int wave = tid >> 6;
  const int nb = wave * 96;
  const int l15 = lane & 15, quad = lane >> 4;

  f32x4 acc[4][6] = {};
  float4 areg[8];

#define LOAD_A(KT)                                                         \
  do {                                                                     \
    _Pragma("unroll") for (int r = 0; r < 8; ++r) {                        \
      int c = r * 256 + tid;                                               \
      int row = c >> 5, col = (c & 31) * 4;                                \
      areg[r] = *(const float4*)&x[(size_t)(m0 + row) * SEQ + (KT) + col]; \
    }                                                                      \
  } while (0)

  LOAD_A(k0);

  for (int kt = k0; kt < k0 + kc; kt += 128) {
    // A: prefetched regs -> f16 -> LDS (128-wide tile)
#pragma unroll
    for (int r = 0; r < 8; ++r) {
      int c = r * 256 + tid;
      int row = c >> 5, col = (c & 31) * 4;
      f16x4 h; h[0] = (f16)areg[r].x; h[1] = (f16)areg[r].y;
      h[2] = (f16)areg[r].z; h[3] = (f16)areg[r].w;
      *(f16x4*)&Ax[row][col] = h;
    }
    const bool nextA = (kt + 128 < k0 + kc);
#pragma unroll
    for (int h = 0; h < 2; ++h) {
      // B: 12 async DMA issues/thread for this 64-wide half.
#pragma unroll
      for (int r = 0; r < 12; ++r) {
        int c = r * 256 + tid;              // 0..3071 over 384 rows x 8 chunks
        int row = c >> 3, ch = c & 7;
        const f16* src = &Wh[(size_t)row * SEQ + kt + h * 64 + ((ch ^ (row & 7)) << 3)];
        gl_lds16(src, &Bx[(size_t)c << 3]);
      }
      __syncthreads();   // drains vmcnt (incl. DMA) + lgkm
      // T14: prefetch next A tile during the first half's MFMA phase
      if (h == 0 && nextA) LOAD_A(kt + 128);
#pragma unroll
      for (int ks = 0; ks < 2; ++ks) {
        f16x8 a[4], bb[6];
#pragma unroll
        for (int t = 0; t < 4; ++t)
          a[t] = *(const f16x8*)&Ax[t * 16 + l15][h * 64 + ks * 32 + quad * 8];
#pragma unroll
        for (int t = 0; t < 6; ++t) {
          int n = nb + t * 16 + l15;                 // n&7 == l15&7
          int ch = (ks * 4 + quad) ^ (l15 & 7);      // un-swizzle
          bb[t] = *(const f16x8*)&Bx[((size_t)n << 6) + (ch << 3)];
        }
#pragma unroll
        for (int mt = 0; mt < 4; ++mt)
#pragma unroll
          for (int nt = 0; nt < 6; ++nt)
            acc[mt][nt] = __builtin_amdgcn_mfma_f32_16x16x32_f16(a[mt], bb[nt], acc[mt][nt], 0, 0, 0);
      }
      __syncthreads();
    }
  }
#undef LOAD_A

  // epilogue: register-layout partials, f16x4 b64 coalesced stores
  f16* pw = part + (((size_t)split * 64 + bx) * 24) * 256 * 4;
#pragma unroll
  for (int mt = 0; mt < 4; ++mt) {
#pragma unroll
    for (int nt = 0; nt < 6; ++nt) {
      int p = mt * 6 + nt;
      f16x4 h;
#pragma unroll
      for (int rr = 0; rr < 4; ++rr) h[rr] = (f16)acc[mt][nt][rr];
      *(f16x4*)&pw[((size_t)p * 256 + tid) * 4] = h;
    }
  }

  // ---- last-block-done stripe reduction (split-K fusion) ----
  __threadfence();               // release: partials visible device-wide
  if (tid == 0) {
    int c = atomicAdd(&cnt[bx], 1);
    amLast = (c == SPLITS - 1);
  }
  __syncthreads();
  if (!amLast) return;
  __threadfence();               // acquire: other blocks' partials

#pragma unroll
  for (int mt = 0; mt < 4; ++mt) {
    const int rowl = mt * 16 + quad * 4;
    const int rowbase = m0 + rowl;
#pragma unroll
    for (int nt = 0; nt < 6; ++nt) {
      const int p = mt * 6 + nt;
      float racc[4] = {0.f, 0.f, 0.f, 0.f};
#pragma unroll
      for (int s = 0; s < SPLITS; ++s) {
        f16x4 v = *(const f16x4*)&part[((((size_t)s * 64 + bx) * 24 + p) * 256 + tid) * 4];
#pragma unroll
        for (int rr = 0; rr < 4; ++rr) racc[rr] += (float)v[rr];
      }
      int col = nb + nt * 16 + l15;
      float bv = bias[col];
      if (col < 128) {
#pragma unroll
        for (int rr = 0; rr < 4; ++rr)
          qkv[(size_t)(rowbase + rr) * QKV_LD + col] = (f16)((racc[rr] + bv) * LOG2E);
      } else if (col < 256) {
#pragma unroll
        for (int rr = 0; rr < 4; ++rr)
          qkv[(size_t)(rowbase + rr) * QKV_LD + col] = (f16)(racc[rr] + bv);
      } else {
        f16x4 h;
#pragma unroll
        for (int rr = 0; rr < 4; ++rr) h[rr] = (f16)(racc[rr] + bv);
        *(f16x4*)&Vl[col - 256][rowl] = h;
      }
    }
  }
  __syncthreads();
  // V write-out: 8 lanes cover one d-row (128B contiguous per d)
#pragma unroll
  for (int j = 0; j < 4; ++j) {
    int c = j * 256 + tid;           // 0..1023
    int d = c >> 3, seg = c & 7;
    f16x8 v = *(const f16x8*)&Vl[d][seg * 8];
    *(f16x8*)&Vt[(size_t)d * SEQ + m0 + seg * 8] = v;
  }
}

// ---------------- Flash attention partial over a KV split ----------------
#define NSPLIT 16
#define KVRANGE (SEQ / NSPLIT)   // 256

// shared memory partition (f16 units):
//   Ks: [0, 8704)           64 x 136
//   Vs: [8704, 17920)       128 x 72
//   Ps: [17920, 27136)      4 waves x 32 x 72
//   Os: [0, 17408)          128 x 136 (reuses Ks+Vs after last barrier)
__global__ __launch_bounds__(256, 2) void attn_partial(const f16* __restrict__ qkv,
                                                       const f16* __restrict__ Vt,
                                                       f16* __restrict__ Op,
                                                       float* __restrict__ ml) {
  __shared__ __align__(16) f16 smem[27136];
  f16* Ks = smem;                    // row stride 136
  f16* Vs = smem + 8704;             // row stride 72
  f16* Ps = smem + 17920;            // per-wave 32x72

  const int q0 = blockIdx.x * 128;
  const int split = blockIdx.y;
  const int kv0 = split * KVRANGE;
  const int tid = threadIdx.x;
  const int lane = tid & 63, wave = tid >> 6;
  const int l15 = lane & 15, quad = lane >> 4;
  const int mbase = q0 + wave * 32;
  f16* Psw = Ps + wave * 32 * 72;

  // Q fragments (pre-scaled by log2(e) in the fused reduce): B-operand of S^T = K·Q^T
  f16x8 qf[2][4];
#pragma unroll
  for (int mt = 0; mt < 2; ++mt)
#pragma unroll
    for (int ks = 0; ks < 4; ++ks)
      qf[mt][ks] = *(const f16x8*)&qkv[(size_t)(mbase + mt * 16 + l15) * QKV_LD + ks * 32 + quad * 8];

  f32x4 oacc[2][8] = {};
  float mrow[2] = {-1e30f, -1e30f};
  float lrow[2] = {0.f, 0.f};

  // T14: K/V tile prefetched into regs; LDS-write at top of iter, loads for
  // the NEXT tile issued right after the barrier (hidden under compute).
  f16x8 kreg[4], vreg[4];
#define LOAD_TILE(K0)                                                                  \
  do {                                                                                 \
    _Pragma("unroll") for (int r = 0; r < 4; ++r) {                                    \
      int c = tid + r * 256;                                                           \
      int row = c >> 4, col = (c & 15) * 8;                                            \
      kreg[r] = *(const f16x8*)&qkv[(size_t)((K0) + row) * QKV_LD + DH + col];         \
    }                                                                                  \
    _Pragma("unroll") for (int r = 0; r < 4; ++r) {                                    \
      int c = tid + r * 256;                                                           \
      int row = c >> 3, col = (c & 7) * 8;                                             \
      vreg[r] = *(const f16x8*)&Vt[(size_t)row * SEQ + (K0) + col];                    \
    }                                                                                  \
  } while (0)

  LOAD_TILE(kv0);

  for (int it = 0; it < KVRANGE / 64; ++it) {
#pragma unroll
    for (int r = 0; r < 4; ++r) {
      int c = tid + r * 256;
      int row = c >> 4, col = (c & 15) * 8;
      *(f16x8*)&Ks[row * 136 + col] = kreg[r];
    }
#pragma unroll
    for (int r = 0; r < 4; ++r) {
      int c = tid + r * 256;
      int row = c >> 3, col = (c & 7) * 8;
      *(f16x8*)&Vs[row * 72 + col] = vreg[r];
    }
    __syncthreads();
    if (it + 1 < KVRANGE / 64) { int k0n = kv0 + (it + 1) * 64; LOAD_TILE(k0n); }

    // S^T[k][m]: A=K-frag, B=Q-frag. Lane holds S[m=l15(+mt*16)][k=kt*16+quad*4+rr].
    f32x4 st[4][2] = {};   // [kt][mt]
    __builtin_amdgcn_s_setprio(1);   // T5: favor this wave while MFMA-dense
#pragma unroll
    for (int ks = 0; ks < 4; ++ks) {
      f16x8 kf[4];
#pragma unroll
      for (int kt = 0; kt < 4; ++kt)
        kf[kt] = *(const f16x8*)&Ks[(kt * 16 + l15) * 136 + ks * 32 + quad * 8];
#pragma unroll
      for (int kt = 0; kt < 4; ++kt)
#pragma unroll
        for (int mt = 0; mt < 2; ++mt)
          st[kt][mt] = __builtin_amdgcn_mfma_f32_16x16x32_f16(kf[kt], qf[mt][ks], st[kt][mt], 0, 0, 0);
    }
    __builtin_amdgcn_s_setprio(0);

    // online softmax with T13 defer-max: skip rescale while max growth <= THR
    float vmax[2];
#pragma unroll
    for (int mt = 0; mt < 2; ++mt) {
      float v = -1e30f;
#pragma unroll
      for (int kt = 0; kt < 4; ++kt)
#pragma unroll
        for (int rr = 0; rr < 4; ++rr) v = fmaxf(v, st[kt][mt][rr]);
      v = fmaxf(v, __shfl_xor(v, 16));
      v = fmaxf(v, __shfl_xor(v, 32));
      vmax[mt] = v;
    }
    bool ok = (vmax[0] <= mrow[0] + DEFER_THR) & (vmax[1] <= mrow[1] + DEFER_THR);
    if (!__all(ok)) {
      float al[2];
#pragma unroll
      for (int mt = 0; mt < 2; ++mt) {
        float mnew = fmaxf(mrow[mt], vmax[mt]);
        al[mt] = fast_exp2(mrow[mt] - mnew);
        mrow[mt] = mnew;
        lrow[mt] *= al[mt];
      }
      float alr[2][4];
#pragma unroll
      for (int mt = 0; mt < 2; ++mt)
#pragma unroll
        for (int rr = 0; rr < 4; ++rr)
          alr[mt][rr] = __shfl(al[mt], quad * 4 + rr);
#pragma unroll
      for (int mt = 0; mt < 2; ++mt)
#pragma unroll
        for (int dt = 0; dt < 8; ++dt)
#pragma unroll
          for (int rr = 0; rr < 4; ++rr)
            oacc[mt][dt][rr] *= alr[mt][rr];
    }
#pragma unroll
    for (int mt = 0; mt < 2; ++mt) {
      float ls = 0.f;
#pragma unroll
      for (int kt = 0; kt < 4; ++kt) {
        f16x4 pk;
#pragma unroll
        for (int rr = 0; rr < 4; ++rr) {
          float p = fast_exp2(st[kt][mt][rr] - mrow[mt]);
          ls += p;
          pk[rr] = (f16)p;
        }
        *(f16x4*)&Psw[(mt * 16 + l15) * 72 + kt * 16 + quad * 4] = pk;
      }
      ls += __shfl_xor(ls, 16);
      ls += __shfl_xor(ls, 32);
      lrow[mt] += ls;
    }

    // PV: A=P-frag (b128 from Ps[m][k]), B=V^T-frag (b128 from Vs[d][k])
    __builtin_amdgcn_s_setprio(1);
#pragma unroll
    for (int kk = 0; kk < 2; ++kk) {
      f16x8 pf[2];
#pragma unroll
      for (int mt = 0; mt < 2; ++mt)
        pf[mt] = *(const f16x8*)&Psw[(mt * 16 + l15) * 72 + kk * 32 + quad * 8];
#pragma unroll
      for (int dt = 0; dt < 8; ++dt) {
        f16x8 vf = *(const f16x8*)&Vs[(dt * 16 + l15) * 72 + kk * 32 + quad * 8];
#pragma unroll
        for (int mt = 0; mt < 2; ++mt)
          oacc[mt][dt] = __builtin_amdgcn_mfma_f32_16x16x32_f16(pf[mt], vf, oacc[mt][dt], 0, 0, 0);
      }
    }
    __builtin_amdgcn_s_setprio(0);
    __syncthreads();
  }
#undef LOAD_TILE

  // O epilogue via LDS (reuses Ks+Vs region): scalar LDS stores, then
  // fully-coalesced b128 global stores.
  f16* Os = smem;   // [128][136]
#pragma unroll
  for (int mt = 0; mt < 2; ++mt)
#pragma unroll
    for (int dt = 0; dt < 8; ++dt)
#pragma unroll
      for (int rr = 0; rr < 4; ++rr)
        Os[(wave * 32 + mt * 16 + quad * 4 + rr) * 136 + dt * 16 + l15] = (f16)oacc[mt][dt][rr];
  if (quad == 0) {
#pragma unroll
    for (int mt = 0; mt < 2; ++mt) {
      int row = mbase + mt * 16 + l15;
      ml[((size_t)split * SEQ + row) * 2 + 0] = mrow[mt];
      ml[((size_t)split * SEQ + row) * 2 + 1] = lrow[mt];
    }
  }
  __syncthreads();
#pragma unroll
  for (int j = 0; j < 8; ++j) {
    int c = j * 256 + tid;
    int row = c >> 4, ch = c & 15;
    f16x8 v = *(const f16x8*)&Os[row * 136 + ch * 8];
    *(f16x8*)&Op[((size_t)split * SEQ + q0 + row) * DH + ch * 8] = v;
  }
}

// ---------------- combine KV splits (vectorized: 8 elems/thread) ----------------
__global__ __launch_bounds__(256) void combine_kernel(const f16* __restrict__ Op,
                                                      const float* __restrict__ ml,
                                                      float* __restrict__ out) {
  int t = blockIdx.x * 256 + threadIdx.x;
  int base = t * 8;
  int row = base >> 7;
  float ms[NSPLIT], ls[NSPLIT];
  float M = -1e30f;
#pragma unroll
  for (int s = 0; s < NSPLIT; ++s) {
    float2 v = *(const float2*)&ml[((size_t)s * SEQ + row) * 2];
    ms[s] = v.x; ls[s] = v.y;
    M = fmaxf(M, v.x);
  }
  float L = 0.f;
  float o[8] = {};
#pragma unroll
  for (int s = 0; s < NSPLIT; ++s) {
    float w = fast_exp2(ms[s] - M);
    L += ls[s] * w;
    f16x8 v = *(const f16x8*)&Op[(size_t)s * SEQ * DH + base];
#pragma unroll
    for (int j = 0; j < 8; ++j) o[j] += w * (float)v[j];
  }
  float inv = 1.0f / L;
  float4 o0, o1;
  o0.x = o[0] * inv; o0.y = o[1] * inv; o0.z = o[2] * inv; o0.w = o[3] * inv;
  o1.x = o[4] * inv; o1.y = o[5] * inv; o1.z = o[6] * inv; o1.w = o[7] * inv;
  *(float4*)&out[base] = o0;
  *(float4*)&out[base + 4] = o1;
}

extern "C" void kernel_launch(void* const* d_in, const int* in_sizes, int n_in,
                              void* d_out, int out_size, void* d_ws, size_t ws_size,
                              hipStream_t stream) {
  const float* x = (const float*)d_in[0];
  const float* W = (const float*)d_in[1];
  const float* b = (const float*)d_in[2];
  float* out = (float*)d_out;
  char* ws = (char*)d_ws;

  f16*   Wh   = (f16*)(ws);                      // [0, 3M)
  f16*   qkv  = (f16*)(ws + (3u << 20));         // [3M, 6M)
  f16*   Vt   = (f16*)(ws + (6u << 20));         // [6M, 7M)
  float* ml   = (float*)(ws + (7u << 20));       // [7M, 7.5M)
  char*  scr  = ws + (7u << 20) + (1u << 19);    // cnt + gemm partials / attn Op
  int*   cnt  = (int*)scr;                       // 64 ints (zeroed by cvt_w)
  f16*   part = (f16*)(scr + 4096);              // SPLITS * 3MB
  f16*   Op   = (f16*)(scr + 4096);              // 16 MB (reuses partials region)

  cvt_w_kernel<<<(384 * 4096 / 4) / 256, 256, 0, stream>>>((const float4*)W, (f16x4*)Wh, cnt);

  bool big = ws_size >= ((size_t)31u << 20) + ((size_t)1u << 19) + 4096;
  if (big) {
    gemm_qkv_fused<8><<<dim3(SEQ / 64, 8), 256, 0, stream>>>(x, Wh, b, part, cnt, qkv, Vt);
  } else {
    gemm_qkv_fused<4><<<dim3(SEQ / 64, 4), 256, 0, stream>>>(x, Wh, b, part, cnt, qkv, Vt);
  }
  attn_partial<<<dim3(SEQ / 128, NSPLIT), 256, 0, stream>>>(qkv, Vt, Op, ml);
  combine_kernel<<<(SEQ * DH) / 8 / 256, 256, 0, stream>>>(Op, ml, out);
}

// Round 7
// 164.771 us; speedup vs baseline: 1.3603x; 1.3603x over previous
//
#include <hip/hip_runtime.h>
#include <cstdint>
#include <cstddef>

typedef _Float16 f16;
typedef f16 f16x8 __attribute__((ext_vector_type(8)));
typedef f16 f16x4 __attribute__((ext_vector_type(4)));
typedef float f32x4 __attribute__((ext_vector_type(4)));

#define SEQ 4096
#define DH 128
#define QKV_LD 384   // 3*DH
#define LOG2E 1.44269504f
#define DEFER_THR 4.0f

__device__ __forceinline__ float fast_exp2(float x) {
#if __has_builtin(__builtin_amdgcn_exp2f)
  return __builtin_amdgcn_exp2f(x);
#else
  return exp2f(x);
#endif
}

// async global->LDS DMA, 16B per lane. LDS dest MUST be wave-uniform base + lane*16.
__device__ __forceinline__ void gl_lds16(const void* g, void* l) {
  __builtin_amdgcn_global_load_lds((const __attribute__((address_space(1))) void*)g,
                                   (__attribute__((address_space(3))) void*)l, 16, 0, 0);
}

// ---------------- W fp32 -> fp16 ----------------
__global__ __launch_bounds__(256) void cvt_w_kernel(const float4* __restrict__ W,
                                                    f16x4* __restrict__ Wh) {
  int i = blockIdx.x * 256 + threadIdx.x;
  float4 v = W[i];
  f16x4 h; h[0] = (f16)v.x; h[1] = (f16)v.y; h[2] = (f16)v.z; h[3] = (f16)v.w;
  Wh[i] = h;
}

// ---------------- QKV GEMM, split-K, full-N per block ----------------
// BM=64, BN=384. A staged at BK=128 (512B contiguous per x row); B/MFMA inner
// loop runs two 64-wide halves. Grid (64, SPLITS) = 512 blocks -> 2 blocks/CU.
// B staged by global_load_lds into unpadded XOR-swizzled LDS; A prefetched in
// regs (T14). Partials in REGISTER layout ([split][mblk][p24][tid][4], f16x4).
template <int SPLITS>
__global__ __launch_bounds__(256, 2) void gemm_qkv(const float* __restrict__ x,
                                                   const f16* __restrict__ Wh,
                                                   f16* __restrict__ part) {
  __shared__ __align__(16) f16 Ax[64][136];         // 128 cols + 8 pad: 272B row stride
  __shared__ __align__(16) f16 Bx[QKV_LD * 64];     // unpadded 384x64, swizzled chunks
  const int m0 = blockIdx.x * 64;
  const int split = blockIdx.y;
  const int kc = SEQ / SPLITS;
  const int k0 = split * kc;
  const int tid = threadIdx.x;
  const int lane = tid & 63;
  const int wave = tid >> 6;
  const int nb = wave * 96;
  const int l15 = lane & 15, quad = lane >> 4;

  f32x4 acc[4][6] = {};
  float4 areg[8];

#define LOAD_A(KT)                                                         \
  do {                                                                     \
    _Pragma("unroll") for (int r = 0; r < 8; ++r) {                        \
      int c = r * 256 + tid;                                               \
      int row = c >> 5, col = (c & 31) * 4;                                \
      areg[r] = *(const float4*)&x[(size_t)(m0 + row) * SEQ + (KT) + col]; \
    }                                                                      \
  } while (0)

  LOAD_A(k0);

  for (int kt = k0; kt < k0 + kc; kt += 128) {
    // A: prefetched regs -> f16 -> LDS (128-wide tile)
#pragma unroll
    for (int r = 0; r < 8; ++r) {
      int c = r * 256 + tid;
      int row = c >> 5, col = (c & 31) * 4;
      f16x4 h; h[0] = (f16)areg[r].x; h[1] = (f16)areg[r].y;
      h[2] = (f16)areg[r].z; h[3] = (f16)areg[r].w;
      *(f16x4*)&Ax[row][col] = h;
    }
    const bool nextA = (kt + 128 < k0 + kc);
#pragma unroll
    for (int h = 0; h < 2; ++h) {
      // B: 12 async DMA issues/thread for this 64-wide half.
#pragma unroll
      for (int r = 0; r < 12; ++r) {
        int c = r * 256 + tid;              // 0..3071 over 384 rows x 8 chunks
        int row = c >> 3, ch = c & 7;
        const f16* src = &Wh[(size_t)row * SEQ + kt + h * 64 + ((ch ^ (row & 7)) << 3)];
        gl_lds16(src, &Bx[(size_t)c << 3]);
      }
      __syncthreads();   // drains vmcnt (incl. DMA) + lgkm
      // T14: prefetch next A tile during the first half's MFMA phase
      if (h == 0 && nextA) LOAD_A(kt + 128);
#pragma unroll
      for (int ks = 0; ks < 2; ++ks) {
        f16x8 a[4], bb[6];
#pragma unroll
        for (int t = 0; t < 4; ++t)
          a[t] = *(const f16x8*)&Ax[t * 16 + l15][h * 64 + ks * 32 + quad * 8];
#pragma unroll
        for (int t = 0; t < 6; ++t) {
          int n = nb + t * 16 + l15;                 // n&7 == l15&7
          int ch = (ks * 4 + quad) ^ (l15 & 7);      // un-swizzle
          bb[t] = *(const f16x8*)&Bx[((size_t)n << 6) + (ch << 3)];
        }
#pragma unroll
        for (int mt = 0; mt < 4; ++mt)
#pragma unroll
          for (int nt = 0; nt < 6; ++nt)
            acc[mt][nt] = __builtin_amdgcn_mfma_f32_16x16x32_f16(a[mt], bb[nt], acc[mt][nt], 0, 0, 0);
      }
      __syncthreads();
    }
  }
#undef LOAD_A

  // epilogue: register-layout partials, f16x4 b64 coalesced stores
  f16* pw = part + (((size_t)split * 64 + blockIdx.x) * 24) * 256 * 4;
#pragma unroll
  for (int mt = 0; mt < 4; ++mt) {
#pragma unroll
    for (int nt = 0; nt < 6; ++nt) {
      int p = mt * 6 + nt;
      f16x4 h;
#pragma unroll
      for (int rr = 0; rr < 4; ++rr) h[rr] = (f16)acc[mt][nt][rr];
      *(f16x4*)&pw[((size_t)p * 256 + tid) * 4] = h;
    }
  }
}

// ---------------- reduce split-K partials + bias -> qkv (Q,K) and Vt (V^T) ----
// Decodes the gemm register layout. Grid (64, 4): blockIdx.x = 64-row stripe,
// blockIdx.y = 16-row mt sub-stripe (256 blocks -> full machine).
// Q columns (<128) are pre-scaled by log2(e) so attn skips the per-block scale.
// V columns (256..383) go through a small LDS transpose tile and are written
// directly to Vt[128][4096].
template <int SPLITS>
__global__ __launch_bounds__(256) void reduce_qkv(const f16* __restrict__ part,
                                                  const float* __restrict__ bias,
                                                  f16* __restrict__ qkv,
                                                  f16* __restrict__ Vt) {
  __shared__ __align__(16) f16 Vl[128][24];   // [d][16 rows + 8 pad]
  const int bx = blockIdx.x;
  const int mt = blockIdx.y;
  const int tid = threadIdx.x;
  const int lane = tid & 63, wave = tid >> 6;
  const int l15 = lane & 15, quad = lane >> 4;
  const int rowl = quad * 4;
  const int rowbase = bx * 64 + mt * 16 + rowl;

#pragma unroll
  for (int nt = 0; nt < 6; ++nt) {
    const int p = mt * 6 + nt;
    float acc[4] = {0.f, 0.f, 0.f, 0.f};
#pragma unroll
    for (int s = 0; s < SPLITS; ++s) {
      f16x4 v = *(const f16x4*)&part[((((size_t)s * 64 + bx) * 24 + p) * 256 + tid) * 4];
#pragma unroll
      for (int rr = 0; rr < 4; ++rr) acc[rr] += (float)v[rr];
    }
    int col = wave * 96 + nt * 16 + l15;
    float bv = bias[col];
    if (col < 128) {
#pragma unroll
      for (int rr = 0; rr < 4; ++rr)
        qkv[(size_t)(rowbase + rr) * QKV_LD + col] = (f16)((acc[rr] + bv) * LOG2E);
    } else if (col < 256) {
#pragma unroll
      for (int rr = 0; rr < 4; ++rr)
        qkv[(size_t)(rowbase + rr) * QKV_LD + col] = (f16)(acc[rr] + bv);
    } else {
      f16x4 h;
#pragma unroll
      for (int rr = 0; rr < 4; ++rr) h[rr] = (f16)(acc[rr] + bv);
      *(f16x4*)&Vl[col - 256][rowl] = h;
    }
  }
  __syncthreads();
  // write-out: 128 d x 16 rows = 8 f16/thread; lane pairs give 32B-contiguous runs
  {
    int d = tid >> 1, seg = tid & 1;
    f16x8 v = *(const f16x8*)&Vl[d][seg * 8];
    *(f16x8*)&Vt[(size_t)d * SEQ + bx * 64 + mt * 16 + seg * 8] = v;
  }
}

// ---------------- Flash attention partial over a KV split ----------------
// K and V are read DIRECTLY from global (L2/L3-resident: qkv 3MB + Vt 1MB,
// shared across all q-blocks of a split -> m169 lesson: don't stage what
// cache-fits). Only wave-private Ps lives in LDS -> ZERO barriers in the
// main loop; waves run fully unsynchronized.
#define NSPLIT 16
#define KVRANGE (SEQ / NSPLIT)   // 256

// smem: Ps = 4 waves x 32 x 72 (9216 f16) during loop;
//       Os = 128 x 136 (17408 f16) at epilogue (aliases Ps; barrier-guarded).
__global__ __launch_bounds__(256, 2) void attn_partial(const f16* __restrict__ qkv,
                                                       const f16* __restrict__ Vt,
                                                       f16* __restrict__ Op,
                                                       float* __restrict__ ml) {
  __shared__ __align__(16) f16 smem[17408];

  const int q0 = blockIdx.x * 128;
  const int split = blockIdx.y;
  const int kv0 = split * KVRANGE;
  const int tid = threadIdx.x;
  const int lane = tid & 63, wave = tid >> 6;
  const int l15 = lane & 15, quad = lane >> 4;
  const int mbase = q0 + wave * 32;
  f16* Psw = smem + wave * 32 * 72;

  // Q fragments (pre-scaled by log2(e) in reduce_qkv): B-operand of S^T = K·Q^T
  f16x8 qf[2][4];
#pragma unroll
  for (int mt = 0; mt < 2; ++mt)
#pragma unroll
    for (int ks = 0; ks < 4; ++ks)
      qf[mt][ks] = *(const f16x8*)&qkv[(size_t)(mbase + mt * 16 + l15) * QKV_LD + ks * 32 + quad * 8];

  f32x4 oacc[2][8] = {};
  float mrow[2] = {-1e30f, -1e30f};
  float lrow[2] = {0.f, 0.f};

  for (int it = 0; it < KVRANGE / 64; ++it) {
    const int k0 = kv0 + it * 64;

    // S^T[k][m]: A=K-frag (direct global, 16 rows x 64B contiguous per load),
    // B=Q-frag. Lane holds S[m=l15(+mt*16)][k=kt*16+quad*4+rr].
    f32x4 st[4][2] = {};   // [kt][mt]
    __builtin_amdgcn_s_setprio(1);   // T5: favor this wave while MFMA-dense
#pragma unroll
    for (int ks = 0; ks < 4; ++ks) {
      f16x8 kf[4];
#pragma unroll
      for (int kt = 0; kt < 4; ++kt)
        kf[kt] = *(const f16x8*)&qkv[(size_t)(k0 + kt * 16 + l15) * QKV_LD + DH + ks * 32 + quad * 8];
#pragma unroll
      for (int kt = 0; kt < 4; ++kt)
#pragma unroll
        for (int mt = 0; mt < 2; ++mt)
          st[kt][mt] = __builtin_amdgcn_mfma_f32_16x16x32_f16(kf[kt], qf[mt][ks], st[kt][mt], 0, 0, 0);
    }
    __builtin_amdgcn_s_setprio(0);

    // online softmax with T13 defer-max: skip rescale while max growth <= THR
    float vmax[2];
#pragma unroll
    for (int mt = 0; mt < 2; ++mt) {
      float v = -1e30f;
#pragma unroll
      for (int kt = 0; kt < 4; ++kt)
#pragma unroll
        for (int rr = 0; rr < 4; ++rr) v = fmaxf(v, st[kt][mt][rr]);
      v = fmaxf(v, __shfl_xor(v, 16));
      v = fmaxf(v, __shfl_xor(v, 32));
      vmax[mt] = v;
    }
    bool ok = (vmax[0] <= mrow[0] + DEFER_THR) & (vmax[1] <= mrow[1] + DEFER_THR);
    if (!__all(ok)) {
      float al[2];
#pragma unroll
      for (int mt = 0; mt < 2; ++mt) {
        float mnew = fmaxf(mrow[mt], vmax[mt]);
        al[mt] = fast_exp2(mrow[mt] - mnew);
        mrow[mt] = mnew;
        lrow[mt] *= al[mt];
      }
      float alr[2][4];
#pragma unroll
      for (int mt = 0; mt < 2; ++mt)
#pragma unroll
        for (int rr = 0; rr < 4; ++rr)
          alr[mt][rr] = __shfl(al[mt], quad * 4 + rr);
#pragma unroll
      for (int mt = 0; mt < 2; ++mt)
#pragma unroll
        for (int dt = 0; dt < 8; ++dt)
#pragma unroll
          for (int rr = 0; rr < 4; ++rr)
            oacc[mt][dt][rr] *= alr[mt][rr];
    }
#pragma unroll
    for (int mt = 0; mt < 2; ++mt) {
      float ls = 0.f;
#pragma unroll
      for (int kt = 0; kt < 4; ++kt) {
        f16x4 pk;
#pragma unroll
        for (int rr = 0; rr < 4; ++rr) {
          float p = fast_exp2(st[kt][mt][rr] - mrow[mt]);
          ls += p;
          pk[rr] = (f16)p;
        }
        *(f16x4*)&Psw[(mt * 16 + l15) * 72 + kt * 16 + quad * 4] = pk;
      }
      ls += __shfl_xor(ls, 16);
      ls += __shfl_xor(ls, 32);
      lrow[mt] += ls;
    }

    // PV: A=P-frag (b128 from wave-private Ps), B=V^T-frag (direct global,
    // 16 rows x 64B contiguous per load); O standard layout.
    __builtin_amdgcn_s_setprio(1);
#pragma unroll
    for (int kk = 0; kk < 2; ++kk) {
      f16x8 pf[2];
#pragma unroll
      for (int mt = 0; mt < 2; ++mt)
        pf[mt] = *(const f16x8*)&Psw[(mt * 16 + l15) * 72 + kk * 32 + quad * 8];
#pragma unroll
      for (int dt = 0; dt < 8; ++dt) {
        f16x8 vf = *(const f16x8*)&Vt[(size_t)(dt * 16 + l15) * SEQ + k0 + kk * 32 + quad * 8];
#pragma unroll
        for (int mt = 0; mt < 2; ++mt)
          oacc[mt][dt] = __builtin_amdgcn_mfma_f32_16x16x32_f16(pf[mt], vf, oacc[mt][dt], 0, 0, 0);
      }
    }
    __builtin_amdgcn_s_setprio(0);
  }

  // O epilogue via LDS (Os aliases Ps -> barrier before overwrite), then
  // fully-coalesced b128 global stores.
  if (quad == 0) {
#pragma unroll
    for (int mt = 0; mt < 2; ++mt) {
      int row = mbase + mt * 16 + l15;
      ml[((size_t)split * SEQ + row) * 2 + 0] = mrow[mt];
      ml[((size_t)split * SEQ + row) * 2 + 1] = lrow[mt];
    }
  }
  __syncthreads();   // all waves done reading their Ps
  f16* Os = smem;    // [128][136]
#pragma unroll
  for (int mt = 0; mt < 2; ++mt)
#pragma unroll
    for (int dt = 0; dt < 8; ++dt)
#pragma unroll
      for (int rr = 0; rr < 4; ++rr)
        Os[(wave * 32 + mt * 16 + quad * 4 + rr) * 136 + dt * 16 + l15] = (f16)oacc[mt][dt][rr];
  __syncthreads();
#pragma unroll
  for (int j = 0; j < 8; ++j) {
    int c = j * 256 + tid;
    int row = c >> 4, ch = c & 15;
    f16x8 v = *(const f16x8*)&Os[row * 136 + ch * 8];
    *(f16x8*)&Op[((size_t)split * SEQ + q0 + row) * DH + ch * 8] = v;
  }
}

// ---------------- combine KV splits (vectorized: 8 elems/thread) ----------------
__global__ __launch_bounds__(256) void combine_kernel(const f16* __restrict__ Op,
                                                      const float* __restrict__ ml,
                                                      float* __restrict__ out) {
  int t = blockIdx.x * 256 + threadIdx.x;
  int base = t * 8;
  int row = base >> 7;
  float ms[NSPLIT], ls[NSPLIT];
  float M = -1e30f;
#pragma unroll
  for (int s = 0; s < NSPLIT; ++s) {
    float2 v = *(const float2*)&ml[((size_t)s * SEQ + row) * 2];
    ms[s] = v.x; ls[s] = v.y;
    M = fmaxf(M, v.x);
  }
  float L = 0.f;
  float o[8] = {};
#pragma unroll
  for (int s = 0; s < NSPLIT; ++s) {
    float w = fast_exp2(ms[s] - M);
    L += ls[s] * w;
    f16x8 v = *(const f16x8*)&Op[(size_t)s * SEQ * DH + base];
#pragma unroll
    for (int j = 0; j < 8; ++j) o[j] += w * (float)v[j];
  }
  float inv = 1.0f / L;
  float4 o0, o1;
  o0.x = o[0] * inv; o0.y = o[1] * inv; o0.z = o[2] * inv; o0.w = o[3] * inv;
  o1.x = o[4] * inv; o1.y = o[5] * inv; o1.z = o[6] * inv; o1.w = o[7] * inv;
  *(float4*)&out[base] = o0;
  *(float4*)&out[base + 4] = o1;
}

extern "C" void kernel_launch(void* const* d_in, const int* in_sizes, int n_in,
                              void* d_out, int out_size, void* d_ws, size_t ws_size,
                              hipStream_t stream) {
  const float* x = (const float*)d_in[0];
  const float* W = (const float*)d_in[1];
  const float* b = (const float*)d_in[2];
  float* out = (float*)d_out;
  char* ws = (char*)d_ws;

  f16*   Wh   = (f16*)(ws);                      // [0, 3M)
  f16*   qkv  = (f16*)(ws + (3u << 20));         // [3M, 6M)
  f16*   Vt   = (f16*)(ws + (6u << 20));         // [6M, 7M)
  float* ml   = (float*)(ws + (7u << 20));       // [7M, 7.5M)
  char*  scr  = ws + (7u << 20) + (1u << 19);    // gemm partials / attn Op
  f16*   part = (f16*)scr;                       // SPLITS * 3MB
  f16*   Op   = (f16*)scr;                       // 16 MB (reuses partials region)

  cvt_w_kernel<<<(384 * 4096 / 4) / 256, 256, 0, stream>>>((const float4*)W, (f16x4*)Wh);

  bool big = ws_size >= ((size_t)31u << 20) + ((size_t)1u << 19);
  if (big) {
    gemm_qkv<8><<<dim3(SEQ / 64, 8), 256, 0, stream>>>(x, Wh, part);
    reduce_qkv<8><<<dim3(64, 4), 256, 0, stream>>>(part, b, qkv, Vt);
  } else {
    gemm_qkv<4><<<dim3(SEQ / 64, 4), 256, 0, stream>>>(x, Wh, part);
    reduce_qkv<4><<<dim3(64, 4), 256, 0, stream>>>(part, b, qkv, Vt);
  }
  attn_partial<<<dim3(SEQ / 128, NSPLIT), 256, 0, stream>>>(qkv, Vt, Op, ml);
  combine_kernel<<<(SEQ * DH) / 8 / 256, 256, 0, stream>>>(Op, ml, out);
}

// Round 9
// 142.809 us; speedup vs baseline: 1.5695x; 1.1538x over previous
//
#include <hip/hip_runtime.h>
#include <cstdint>
#include <cstddef>

typedef _Float16 f16;
typedef f16 f16x8 __attribute__((ext_vector_type(8)));
typedef f16 f16x4 __attribute__((ext_vector_type(4)));
typedef float f32x4 __attribute__((ext_vector_type(4)));

#define SEQ 4096
#define DH 128
#define QKV_LD 384   // 3*DH
#define LOG2E 1.44269504f
#define DEFER_THR 4.0f

__device__ __forceinline__ float fast_exp2(float x) {
#if __has_builtin(__builtin_amdgcn_exp2f)
  return __builtin_amdgcn_exp2f(x);
#else
  return exp2f(x);
#endif
}

// async global->LDS DMA, 16B per lane. LDS dest MUST be wave-uniform base + lane*16.
__device__ __forceinline__ void gl_lds16(const void* g, void* l) {
  __builtin_amdgcn_global_load_lds((const __attribute__((address_space(1))) void*)g,
                                   (__attribute__((address_space(3))) void*)l, 16, 0, 0);
}

// ---------------- W fp32 -> fp16 ----------------
__global__ __launch_bounds__(256) void cvt_w_kernel(const float4* __restrict__ W,
                                                    f16x4* __restrict__ Wh) {
  int i = blockIdx.x * 256 + threadIdx.x;
  float4 v = W[i];
  f16x4 h; h[0] = (f16)v.x; h[1] = (f16)v.y; h[2] = (f16)v.z; h[3] = (f16)v.w;
  Wh[i] = h;
}

// ---------------- QKV GEMM, split-K, full-N per block ----------------
// BM=64, BN=384. A staged at BK=128 (512B contiguous per x row -> better HBM
// granularity on the 67MB x read); B/MFMA inner loop runs two 64-wide halves.
// Grid (64, SPLITS) = 512 blocks -> 2 blocks/CU. B staged by global_load_lds
// into unpadded XOR-swizzled LDS; A prefetched in regs (T14). Partials in
// REGISTER layout ([split][mblk][p24][tid][4], f16x4 b64) -- reduce_qkv decodes.
template <int SPLITS>
__global__ __launch_bounds__(256, 2) void gemm_qkv(const float* __restrict__ x,
                                                   const f16* __restrict__ Wh,
                                                   f16* __restrict__ part) {
  __shared__ __align__(16) f16 Ax[64][136];         // 128 cols + 8 pad: 272B row stride
  __shared__ __align__(16) f16 Bx[QKV_LD * 64];     // unpadded 384x64, swizzled chunks
  const int m0 = blockIdx.x * 64;
  const int split = blockIdx.y;
  const int kc = SEQ / SPLITS;
  const int k0 = split * kc;
  const int tid = threadIdx.x;
  const int lane = tid & 63;
  const int wave = tid >> 6;
  const int nb = wave * 96;
  const int l15 = lane & 15, quad = lane >> 4;

  f32x4 acc[4][6] = {};
  float4 areg[8];

#define LOAD_A(KT)                                                         \
  do {                                                                     \
    _Pragma("unroll") for (int r = 0; r < 8; ++r) {                        \
      int c = r * 256 + tid;                                               \
      int row = c >> 5, col = (c & 31) * 4;                                \
      areg[r] = *(const float4*)&x[(size_t)(m0 + row) * SEQ + (KT) + col]; \
    }                                                                      \
  } while (0)

  LOAD_A(k0);

  for (int kt = k0; kt < k0 + kc; kt += 128) {
    // A: prefetched regs -> f16 -> LDS (128-wide tile)
#pragma unroll
    for (int r = 0; r < 8; ++r) {
      int c = r * 256 + tid;
      int row = c >> 5, col = (c & 31) * 4;
      f16x4 h; h[0] = (f16)areg[r].x; h[1] = (f16)areg[r].y;
      h[2] = (f16)areg[r].z; h[3] = (f16)areg[r].w;
      *(f16x4*)&Ax[row][col] = h;
    }
    const bool nextA = (kt + 128 < k0 + kc);
#pragma unroll
    for (int h = 0; h < 2; ++h) {
      // B: 12 async DMA issues/thread for this 64-wide half.
#pragma unroll
      for (int r = 0; r < 12; ++r) {
        int c = r * 256 + tid;              // 0..3071 over 384 rows x 8 chunks
        int row = c >> 3, ch = c & 7;
        const f16* src = &Wh[(size_t)row * SEQ + kt + h * 64 + ((ch ^ (row & 7)) << 3)];
        gl_lds16(src, &Bx[(size_t)c << 3]);
      }
      __syncthreads();   // drains vmcnt (incl. DMA) + lgkm
      // T14: prefetch next A tile during the first half's MFMA phase
      if (h == 0 && nextA) LOAD_A(kt + 128);
#pragma unroll
      for (int ks = 0; ks < 2; ++ks) {
        f16x8 a[4], bb[6];
#pragma unroll
        for (int t = 0; t < 4; ++t)
          a[t] = *(const f16x8*)&Ax[t * 16 + l15][h * 64 + ks * 32 + quad * 8];
#pragma unroll
        for (int t = 0; t < 6; ++t) {
          int n = nb + t * 16 + l15;                 // n&7 == l15&7
          int ch = (ks * 4 + quad) ^ (l15 & 7);      // un-swizzle
          bb[t] = *(const f16x8*)&Bx[((size_t)n << 6) + (ch << 3)];
        }
#pragma unroll
        for (int mt = 0; mt < 4; ++mt)
#pragma unroll
          for (int nt = 0; nt < 6; ++nt)
            acc[mt][nt] = __builtin_amdgcn_mfma_f32_16x16x32_f16(a[mt], bb[nt], acc[mt][nt], 0, 0, 0);
      }
      __syncthreads();
    }
  }
#undef LOAD_A

  // epilogue: register-layout partials, f16x4 b64 coalesced stores
  f16* pw = part + (((size_t)split * 64 + blockIdx.x) * 24) * 256 * 4;
#pragma unroll
  for (int mt = 0; mt < 4; ++mt) {
#pragma unroll
    for (int nt = 0; nt < 6; ++nt) {
      int p = mt * 6 + nt;
      f16x4 h;
#pragma unroll
      for (int rr = 0; rr < 4; ++rr) h[rr] = (f16)acc[mt][nt][rr];
      *(f16x4*)&pw[((size_t)p * 256 + tid) * 4] = h;
    }
  }
}

// ---------------- reduce split-K partials + bias -> qkv (Q,K) and Vt (V^T) ----
// Decodes the gemm register layout. Grid (64, 4): blockIdx.x = 64-row stripe,
// blockIdx.y = 16-row mt sub-stripe (256 blocks -> full machine).
// Q columns (<128) are pre-scaled by log2(e) so attn skips the per-block scale.
// V columns (256..383) go through a small LDS transpose tile and are written
// directly to Vt[128][4096]; transpose_v kernel is gone.
template <int SPLITS>
__global__ __launch_bounds__(256) void reduce_qkv(const f16* __restrict__ part,
                                                  const float* __restrict__ bias,
                                                  f16* __restrict__ qkv,
                                                  f16* __restrict__ Vt) {
  __shared__ __align__(16) f16 Vl[128][24];   // [d][16 rows + 8 pad]
  const int bx = blockIdx.x;
  const int mt = blockIdx.y;
  const int tid = threadIdx.x;
  const int lane = tid & 63, wave = tid >> 6;
  const int l15 = lane & 15, quad = lane >> 4;
  const int rowl = quad * 4;
  const int rowbase = bx * 64 + mt * 16 + rowl;

#pragma unroll
  for (int nt = 0; nt < 6; ++nt) {
    const int p = mt * 6 + nt;
    float acc[4] = {0.f, 0.f, 0.f, 0.f};
#pragma unroll
    for (int s = 0; s < SPLITS; ++s) {
      f16x4 v = *(const f16x4*)&part[((((size_t)s * 64 + bx) * 24 + p) * 256 + tid) * 4];
#pragma unroll
      for (int rr = 0; rr < 4; ++rr) acc[rr] += (float)v[rr];
    }
    int col = wave * 96 + nt * 16 + l15;
    float bv = bias[col];
    if (col < 128) {
#pragma unroll
      for (int rr = 0; rr < 4; ++rr)
        qkv[(size_t)(rowbase + rr) * QKV_LD + col] = (f16)((acc[rr] + bv) * LOG2E);
    } else if (col < 256) {
#pragma unroll
      for (int rr = 0; rr < 4; ++rr)
        qkv[(size_t)(rowbase + rr) * QKV_LD + col] = (f16)(acc[rr] + bv);
    } else {
      f16x4 h;
#pragma unroll
      for (int rr = 0; rr < 4; ++rr) h[rr] = (f16)(acc[rr] + bv);
      *(f16x4*)&Vl[col - 256][rowl] = h;
    }
  }
  __syncthreads();
  // write-out: 128 d x 16 rows = 8 f16/thread; lane pairs give 32B-contiguous runs
  {
    int d = tid >> 1, seg = tid & 1;
    f16x8 v = *(const f16x8*)&Vl[d][seg * 8];
    *(f16x8*)&Vt[(size_t)d * SEQ + bx * 64 + mt * 16 + seg * 8] = v;
  }
}

// ---------------- Flash attention partial over a KV split ----------------
#define NSPLIT 16
#define KVRANGE (SEQ / NSPLIT)   // 256

// shared memory partition (f16 units):
//   Ks: [0, 8704)           64 x 136
//   Vs: [8704, 17920)       128 x 72
//   Ps: [17920, 27136)      4 waves x 32 x 72
//   Os: [0, 17408)          128 x 136 (reuses Ks+Vs after last barrier)
__global__ __launch_bounds__(256, 2) void attn_partial(const f16* __restrict__ qkv,
                                                       const f16* __restrict__ Vt,
                                                       f16* __restrict__ Op,
                                                       float* __restrict__ ml) {
  __shared__ __align__(16) f16 smem[27136];
  f16* Ks = smem;                    // row stride 136
  f16* Vs = smem + 8704;             // row stride 72
  f16* Ps = smem + 17920;            // per-wave 32x72

  const int q0 = blockIdx.x * 128;
  const int split = blockIdx.y;
  const int kv0 = split * KVRANGE;
  const int tid = threadIdx.x;
  const int lane = tid & 63, wave = tid >> 6;
  const int l15 = lane & 15, quad = lane >> 4;
  const int mbase = q0 + wave * 32;
  f16* Psw = Ps + wave * 32 * 72;

  // Q fragments (pre-scaled by log2(e) in reduce_qkv): B-operand of S^T = K·Q^T
  f16x8 qf[2][4];
#pragma unroll
  for (int mt = 0; mt < 2; ++mt)
#pragma unroll
    for (int ks = 0; ks < 4; ++ks)
      qf[mt][ks] = *(const f16x8*)&qkv[(size_t)(mbase + mt * 16 + l15) * QKV_LD + ks * 32 + quad * 8];

  f32x4 oacc[2][8] = {};
  float mrow[2] = {-1e30f, -1e30f};
  float lrow[2] = {0.f, 0.f};

  // T14: K/V tile prefetched into regs; LDS-write at top of iter, loads for
  // the NEXT tile issued right after the barrier (hidden under compute).
  f16x8 kreg[4], vreg[4];
#define LOAD_TILE(K0)                                                                  \
  do {                                                                                 \
    _Pragma("unroll") for (int r = 0; r < 4; ++r) {                                    \
      int c = tid + r * 256;                                                           \
      int row = c >> 4, col = (c & 15) * 8;                                            \
      kreg[r] = *(const f16x8*)&qkv[(size_t)((K0) + row) * QKV_LD + DH + col];         \
    }                                                                                  \
    _Pragma("unroll") for (int r = 0; r < 4; ++r) {                                    \
      int c = tid + r * 256;                                                           \
      int row = c >> 3, col = (c & 7) * 8;                                             \
      vreg[r] = *(const f16x8*)&Vt[(size_t)row * SEQ + (K0) + col];                    \
    }                                                                                  \
  } while (0)

  LOAD_TILE(kv0);

  for (int it = 0; it < KVRANGE / 64; ++it) {
#pragma unroll
    for (int r = 0; r < 4; ++r) {
      int c = tid + r * 256;
      int row = c >> 4, col = (c & 15) * 8;
      *(f16x8*)&Ks[row * 136 + col] = kreg[r];
    }
#pragma unroll
    for (int r = 0; r < 4; ++r) {
      int c = tid + r * 256;
      int row = c >> 3, col = (c & 7) * 8;
      *(f16x8*)&Vs[row * 72 + col] = vreg[r];
    }
    __syncthreads();
    if (it + 1 < KVRANGE / 64) { int k0n = kv0 + (it + 1) * 64; LOAD_TILE(k0n); }

    // S^T[k][m]: A=K-frag, B=Q-frag. Lane holds S[m=l15(+mt*16)][k=kt*16+quad*4+rr].
    f32x4 st[4][2] = {};   // [kt][mt]
    __builtin_amdgcn_s_setprio(1);   // T5: favor this wave while MFMA-dense
#pragma unroll
    for (int ks = 0; ks < 4; ++ks) {
      f16x8 kf[4];
#pragma unroll
      for (int kt = 0; kt < 4; ++kt)
        kf[kt] = *(const f16x8*)&Ks[(kt * 16 + l15) * 136 + ks * 32 + quad * 8];
#pragma unroll
      for (int kt = 0; kt < 4; ++kt)
#pragma unroll
        for (int mt = 0; mt < 2; ++mt)
          st[kt][mt] = __builtin_amdgcn_mfma_f32_16x16x32_f16(kf[kt], qf[mt][ks], st[kt][mt], 0, 0, 0);
    }
    __builtin_amdgcn_s_setprio(0);

    // online softmax with T13 defer-max: skip rescale while max growth <= THR
    float vmax[2];
#pragma unroll
    for (int mt = 0; mt < 2; ++mt) {
      float v = -1e30f;
#pragma unroll
      for (int kt = 0; kt < 4; ++kt)
#pragma unroll
        for (int rr = 0; rr < 4; ++rr) v = fmaxf(v, st[kt][mt][rr]);
      v = fmaxf(v, __shfl_xor(v, 16));
      v = fmaxf(v, __shfl_xor(v, 32));
      vmax[mt] = v;
    }
    bool ok = (vmax[0] <= mrow[0] + DEFER_THR) & (vmax[1] <= mrow[1] + DEFER_THR);
    if (!__all(ok)) {
      float al[2];
#pragma unroll
      for (int mt = 0; mt < 2; ++mt) {
        float mnew = fmaxf(mrow[mt], vmax[mt]);
        al[mt] = fast_exp2(mrow[mt] - mnew);
        mrow[mt] = mnew;
        lrow[mt] *= al[mt];
      }
      float alr[2][4];
#pragma unroll
      for (int mt = 0; mt < 2; ++mt)
#pragma unroll
        for (int rr = 0; rr < 4; ++rr)
          alr[mt][rr] = __shfl(al[mt], quad * 4 + rr);
#pragma unroll
      for (int mt = 0; mt < 2; ++mt)
#pragma unroll
        for (int dt = 0; dt < 8; ++dt)
#pragma unroll
          for (int rr = 0; rr < 4; ++rr)
            oacc[mt][dt][rr] *= alr[mt][rr];
    }
#pragma unroll
    for (int mt = 0; mt < 2; ++mt) {
      float ls = 0.f;
#pragma unroll
      for (int kt = 0; kt < 4; ++kt) {
        f16x4 pk;
#pragma unroll
        for (int rr = 0; rr < 4; ++rr) {
          float p = fast_exp2(st[kt][mt][rr] - mrow[mt]);
          ls += p;
          pk[rr] = (f16)p;
        }
        *(f16x4*)&Psw[(mt * 16 + l15) * 72 + kt * 16 + quad * 4] = pk;
      }
      ls += __shfl_xor(ls, 16);
      ls += __shfl_xor(ls, 32);
      lrow[mt] += ls;
    }

    // PV: A=P-frag (b128 from Ps[m][k]), B=V^T-frag (b128 from Vs[d][k])
    __builtin_amdgcn_s_setprio(1);
#pragma unroll
    for (int kk = 0; kk < 2; ++kk) {
      f16x8 pf[2];
#pragma unroll
      for (int mt = 0; mt < 2; ++mt)
        pf[mt] = *(const f16x8*)&Psw[(mt * 16 + l15) * 72 + kk * 32 + quad * 8];
#pragma unroll
      for (int dt = 0; dt < 8; ++dt) {
        f16x8 vf = *(const f16x8*)&Vs[(dt * 16 + l15) * 72 + kk * 32 + quad * 8];
#pragma unroll
        for (int mt = 0; mt < 2; ++mt)
          oacc[mt][dt] = __builtin_amdgcn_mfma_f32_16x16x32_f16(pf[mt], vf, oacc[mt][dt], 0, 0, 0);
      }
    }
    __builtin_amdgcn_s_setprio(0);
    __syncthreads();
  }
#undef LOAD_TILE

  // O epilogue via LDS (reuses Ks+Vs region): scalar LDS stores, then
  // fully-coalesced b128 global stores.
  f16* Os = smem;   // [128][136]
#pragma unroll
  for (int mt = 0; mt < 2; ++mt)
#pragma unroll
    for (int dt = 0; dt < 8; ++dt)
#pragma unroll
      for (int rr = 0; rr < 4; ++rr)
        Os[(wave * 32 + mt * 16 + quad * 4 + rr) * 136 + dt * 16 + l15] = (f16)oacc[mt][dt][rr];
  if (quad == 0) {
#pragma unroll
    for (int mt = 0; mt < 2; ++mt) {
      int row = mbase + mt * 16 + l15;
      ml[((size_t)split * SEQ + row) * 2 + 0] = mrow[mt];
      ml[((size_t)split * SEQ + row) * 2 + 1] = lrow[mt];
    }
  }
  __syncthreads();
#pragma unroll
  for (int j = 0; j < 8; ++j) {
    int c = j * 256 + tid;
    int row = c >> 4, ch = c & 15;
    f16x8 v = *(const f16x8*)&Os[row * 136 + ch * 8];
    *(f16x8*)&Op[((size_t)split * SEQ + q0 + row) * DH + ch * 8] = v;
  }
}

// ---------------- combine KV splits (vectorized: 8 elems/thread) ----------------
__global__ __launch_bounds__(256) void combine_kernel(const f16* __restrict__ Op,
                                                      const float* __restrict__ ml,
                                                      float* __restrict__ out) {
  int t = blockIdx.x * 256 + threadIdx.x;
  int base = t * 8;
  int row = base >> 7;
  float ms[NSPLIT], ls[NSPLIT];
  float M = -1e30f;
#pragma unroll
  for (int s = 0; s < NSPLIT; ++s) {
    float2 v = *(const float2*)&ml[((size_t)s * SEQ + row) * 2];
    ms[s] = v.x; ls[s] = v.y;
    M = fmaxf(M, v.x);
  }
  float L = 0.f;
  float o[8] = {};
#pragma unroll
  for (int s = 0; s < NSPLIT; ++s) {
    float w = fast_exp2(ms[s] - M);
    L += ls[s] * w;
    f16x8 v = *(const f16x8*)&Op[(size_t)s * SEQ * DH + base];
#pragma unroll
    for (int j = 0; j < 8; ++j) o[j] += w * (float)v[j];
  }
  float inv = 1.0f / L;
  float4 o0, o1;
  o0.x = o[0] * inv; o0.y = o[1] * inv; o0.z = o[2] * inv; o0.w = o[3] * inv;
  o1.x = o[4] * inv; o1.y = o[5] * inv; o1.z = o[6] * inv; o1.w = o[7] * inv;
  *(float4*)&out[base] = o0;
  *(float4*)&out[base + 4] = o1;
}

extern "C" void kernel_launch(void* const* d_in, const int* in_sizes, int n_in,
                              void* d_out, int out_size, void* d_ws, size_t ws_size,
                              hipStream_t stream) {
  const float* x = (const float*)d_in[0];
  const float* W = (const float*)d_in[1];
  const float* b = (const float*)d_in[2];
  float* out = (float*)d_out;
  char* ws = (char*)d_ws;

  f16*   Wh   = (f16*)(ws);                      // [0, 3M)
  f16*   qkv  = (f16*)(ws + (3u << 20));         // [3M, 6M)
  f16*   Vt   = (f16*)(ws + (6u << 20));         // [6M, 7M)
  float* ml   = (float*)(ws + (7u << 20));       // [7M, 7.5M)
  char*  scr  = ws + (7u << 20) + (1u << 19);    // gemm partials / attn Op
  f16*   part = (f16*)scr;                       // SPLITS * 3MB
  f16*   Op   = (f16*)scr;                       // 16 MB (reuses partials region)

  cvt_w_kernel<<<(384 * 4096 / 4) / 256, 256, 0, stream>>>((const float4*)W, (f16x4*)Wh);

  bool big = ws_size >= ((size_t)31u << 20) + ((size_t)1u << 19);
  if (big) {
    gemm_qkv<8><<<dim3(SEQ / 64, 8), 256, 0, stream>>>(x, Wh, part);
    reduce_qkv<8><<<dim3(64, 4), 256, 0, stream>>>(part, b, qkv, Vt);
  } else {
    gemm_qkv<4><<<dim3(SEQ / 64, 4), 256, 0, stream>>>(x, Wh, part);
    reduce_qkv<4><<<dim3(64, 4), 256, 0, stream>>>(part, b, qkv, Vt);
  }
  attn_partial<<<dim3(SEQ / 128, NSPLIT), 256, 0, stream>>>(qkv, Vt, Op, ml);
  combine_kernel<<<(SEQ * DH) / 8 / 256, 256, 0, stream>>>(Op, ml, out);
}